// Round 8
// baseline (503.705 us; speedup 1.0000x reference)
//
#include <hip/hip_runtime.h>
#include <math.h>

#define NNODES 50000
#define NEDGES 800000
#define INDIM 256
#define HID 64
#define HEADS 4
#define OUTDIM 64
#define NEG_SLOPE 0.2f
#define NB ((NNODES + 1023) / 1024)   // 49 scan blocks

typedef __attribute__((ext_vector_type(8))) short short8;   // 8 bf16 = 4 VGPRs
typedef __attribute__((ext_vector_type(4))) float f32x4;
typedef _Float16 __attribute__((ext_vector_type(4))) half4;

__device__ inline unsigned short bf16_rtn(float f) {
    unsigned int u = __float_as_uint(f);
    unsigned int r = u + 0x7fffu + ((u >> 16) & 1u);
    return (unsigned short)(r >> 16);
}
__device__ inline float bf16_to_f32(unsigned short h) {
    return __uint_as_float((unsigned int)h << 16);
}

// ---------------- CSR build ----------------

__global__ __launch_bounds__(256) void hist_kernel(const int* __restrict__ dst,
                                                   int* __restrict__ deg) {
    int i = blockIdx.x * 256 + threadIdx.x;
    if (i < NEDGES) atomicAdd(&deg[dst[i]], 1);
}

__global__ __launch_bounds__(256) void bsum_kernel(const int* __restrict__ deg,
                                                   int* __restrict__ bsums) {
    int b = blockIdx.x, t = threadIdx.x;
    int base = b * 1024 + t * 4;
    int s = 0;
    #pragma unroll
    for (int e = 0; e < 4; ++e) { int i = base + e; if (i < NNODES) s += deg[i]; }
    #pragma unroll
    for (int o = 32; o; o >>= 1) s += __shfl_xor(s, o);
    __shared__ int ws[4];
    int lane = t & 63, wid = t >> 6;
    if (lane == 0) ws[wid] = s;
    __syncthreads();
    if (t == 0) bsums[b] = ws[0] + ws[1] + ws[2] + ws[3];
}

__global__ __launch_bounds__(256) void scan_write_kernel(const int* __restrict__ deg,
                                                         const int* __restrict__ bsums,
                                                         int* __restrict__ offs) {
    int b = blockIdx.x, t = threadIdx.x;
    int lane = t & 63, wid = t >> 6;
    int bv = (lane < b) ? bsums[lane] : 0;    // b <= NB-1 < 64
    #pragma unroll
    for (int o = 32; o; o >>= 1) bv += __shfl_xor(bv, o);  // block global offset
    int base = b * 1024 + t * 4;
    int v[4]; int tsum = 0;
    #pragma unroll
    for (int e = 0; e < 4; ++e) {
        int i = base + e;
        v[e] = (i < NNODES) ? deg[i] : 0;
        tsum += v[e];
    }
    int p = tsum;
    #pragma unroll
    for (int o = 1; o < 64; o <<= 1) { int u = __shfl_up(p, o); if (lane >= o) p += u; }
    __shared__ int ws[4];
    if (lane == 63) ws[wid] = p;
    __syncthreads();
    int woff = 0;
    for (int i = 0; i < wid; ++i) woff += ws[i];
    int run = bv + woff + p - tsum;           // exclusive prefix for this thread
    #pragma unroll
    for (int e = 0; e < 4; ++e) {
        int i = base + e;
        if (i < NNODES) { offs[i] = run; run += v[e]; }
    }
    if (b == 0 && t == 0) offs[NNODES] = NEDGES;
}

__global__ __launch_bounds__(256) void scatter_kernel(const int* __restrict__ src,
                                                      const int* __restrict__ dst,
                                                      const int* __restrict__ offs,
                                                      int* __restrict__ cursor,
                                                      int* __restrict__ ssorted) {
    int i = blockIdx.x * 256 + threadIdx.x;
    if (i < NEDGES) {
        int d = dst[i];
        int pos = offs[d] + atomicAdd(&cursor[d], 1);
        ssorted[pos] = src[i];
    }
}

// ---------------- weight transpose+split ----------------
// W [K][N] row-major -> transposed split Wt_hi/Wt_lo [N][K]

__global__ __launch_bounds__(256) void convert_wt_kernel(const float* __restrict__ W,
                                                         unsigned short* __restrict__ hi,
                                                         unsigned short* __restrict__ lo,
                                                         int K, int N) {
    int idx = blockIdx.x * 256 + threadIdx.x;
    if (idx >= K * N) return;
    int k = idx / N, n = idx - k * N;
    float v = W[idx];
    unsigned short h = bf16_rtn(v);
    hi[n * K + k] = h;
    lo[n * K + k] = bf16_rtn(v - bf16_to_f32(h));
}

// ---------------- split-bf16 MFMA GEMM, LDS-free, SMALL TILE ----------------
// R7 post-mortem: 128x128 tile => only 3 waves/SIMD pending, MfmaUtil 9.4%,
// pure latency starvation. R8: 64x64 block tile (4 waves 2x2, 32x32/wave,
// acc = 16 VGPR) => gemm1 grid 3128 blocks = 12.2 waves/SIMD pending, 5-6
// resident. Bt [N][K] pre-split bf16 stays L2-resident. No LDS staging.
// ELR: block covers exactly one head (64 cols); the two wn-halves partial-dot
// their 32 cols and combine through a 512B LDS buffer.

template <int BN, bool PRESPLIT, bool ELR>
__global__ __launch_bounds__(256, 5) void gemm_mfma_kernel(
        const float* __restrict__ Af,
        const unsigned short* __restrict__ Ahi, const unsigned short* __restrict__ Alo,
        const unsigned short* __restrict__ Bthi, const unsigned short* __restrict__ Btlo,
        _Float16* __restrict__ C,
        const float* __restrict__ al, const float* __restrict__ ar,
        float* __restrict__ el, float* __restrict__ er,
        int M, int N, int K) {
    __shared__ float elbuf[64], erbuf[64];
    int t = threadIdx.x;
    int lane = t & 63, w = t >> 6;
    int wm = w >> 1, wn = w & 1;
    int lr = lane & 15, quad = lane >> 4;
    int m0 = blockIdx.y * 64, n0 = blockIdx.x * 64;

    f32x4 acc[2][2];
    #pragma unroll
    for (int i = 0; i < 2; ++i)
        #pragma unroll
        for (int j = 0; j < 2; ++j) acc[i][j] = (f32x4){0.f, 0.f, 0.f, 0.f};

    int arow[2];
    #pragma unroll
    for (int i = 0; i < 2; ++i) {
        int r = m0 + wm * 32 + i * 16 + lr;
        arow[i] = (r < M) ? r : (M - 1);
    }
    int brow[2];
    #pragma unroll
    for (int j = 0; j < 2; ++j) brow[j] = n0 + wn * 32 + j * 16 + lr;

    for (int kk = 0; kk < K; kk += 32) {
        short8 ah[2], av[2], bh[2], bv[2];
        if (PRESPLIT) {
            #pragma unroll
            for (int i = 0; i < 2; ++i) {
                size_t off = (size_t)arow[i] * K + kk + quad * 8;
                ah[i] = *(const short8*)(Ahi + off);
                av[i] = *(const short8*)(Alo + off);
            }
        } else {
            #pragma unroll
            for (int i = 0; i < 2; ++i) {
                const float* ap = Af + (size_t)arow[i] * K + kk + quad * 8;
                float4 f0 = *(const float4*)ap;
                float4 f1 = *(const float4*)(ap + 4);
                float v[8] = {f0.x, f0.y, f0.z, f0.w, f1.x, f1.y, f1.z, f1.w};
                #pragma unroll
                for (int e = 0; e < 8; ++e) {
                    unsigned short h = bf16_rtn(v[e]);
                    ah[i][e] = (short)h;
                    av[i][e] = (short)bf16_rtn(v[e] - bf16_to_f32(h));
                }
            }
        }
        #pragma unroll
        for (int j = 0; j < 2; ++j) {
            size_t off = (size_t)brow[j] * K + kk + quad * 8;
            bh[j] = *(const short8*)(Bthi + off);
            bv[j] = *(const short8*)(Btlo + off);
        }
        #pragma unroll
        for (int i = 0; i < 2; ++i)
            #pragma unroll
            for (int j = 0; j < 2; ++j) {
                acc[i][j] = __builtin_amdgcn_mfma_f32_16x16x32_bf16(ah[i], bh[j], acc[i][j], 0, 0, 0);
                acc[i][j] = __builtin_amdgcn_mfma_f32_16x16x32_bf16(ah[i], bv[j], acc[i][j], 0, 0, 0);
                acc[i][j] = __builtin_amdgcn_mfma_f32_16x16x32_bf16(av[i], bh[j], acc[i][j], 0, 0, 0);
            }
    }
    #pragma unroll
    for (int i = 0; i < 2; ++i) {
        #pragma unroll
        for (int r = 0; r < 4; ++r) {
            int row = m0 + wm * 32 + i * 16 + quad * 4 + r;
            if (row < M) {
                #pragma unroll
                for (int j = 0; j < 2; ++j)
                    C[(size_t)row * N + n0 + wn * 32 + j * 16 + lr] =
                        (_Float16)acc[i][j][r];
            }
        }
    }
    if (ELR) {
        // block covers head h = n0/64; wave half wn covers cols wn*32..+32
        int h = n0 / 64;
        float alh[2], arh[2];
        #pragma unroll
        for (int j = 0; j < 2; ++j) {
            alh[j] = al[h * 64 + wn * 32 + j * 16 + lr];
            arh[j] = ar[h * 64 + wn * 32 + j * 16 + lr];
        }
        float pel_s[2][4], per_s[2][4];
        #pragma unroll
        for (int i = 0; i < 2; ++i) {
            #pragma unroll
            for (int r = 0; r < 4; ++r) {
                float pel = 0.f, per = 0.f;
                #pragma unroll
                for (int j = 0; j < 2; ++j) {
                    pel = fmaf(acc[i][j][r], alh[j], pel);
                    per = fmaf(acc[i][j][r], arh[j], per);
                }
                #pragma unroll
                for (int o = 1; o < 16; o <<= 1) {
                    pel += __shfl_xor(pel, o);
                    per += __shfl_xor(per, o);
                }
                pel_s[i][r] = pel; per_s[i][r] = per;
            }
        }
        if (wn == 1 && lr == 0) {
            #pragma unroll
            for (int i = 0; i < 2; ++i)
                #pragma unroll
                for (int r = 0; r < 4; ++r) {
                    int rl = wm * 32 + i * 16 + quad * 4 + r;
                    elbuf[rl] = pel_s[i][r];
                    erbuf[rl] = per_s[i][r];
                }
        }
        __syncthreads();
        if (wn == 0 && lr == 0) {
            #pragma unroll
            for (int i = 0; i < 2; ++i)
                #pragma unroll
                for (int r = 0; r < 4; ++r) {
                    int rl = wm * 32 + i * 16 + quad * 4 + r;
                    int row = m0 + rl;
                    if (row < M) {
                        el[row * HEADS + h] = pel_s[i][r] + elbuf[rl];
                        er[row * HEADS + h] = per_s[i][r] + erbuf[rl];
                    }
                }
        }
    }
}

// ---------------- layer-2 attention dot products ----------------

__global__ __launch_bounds__(64) void elr2_kernel(const _Float16* __restrict__ feat,
                                                  const float* __restrict__ al,
                                                  const float* __restrict__ ar,
                                                  float* __restrict__ el,
                                                  float* __restrict__ er) {
    int n = blockIdx.x, d = threadIdx.x;
    float f = (float)feat[(size_t)n * 64 + d];
    float a = f * al[d], b = f * ar[d];
    #pragma unroll
    for (int o = 32; o; o >>= 1) { a += __shfl_xor(a, o); b += __shfl_xor(b, o); }
    if (d == 0) { el[n] = a; er[n] = b; }
}

// ---------------- softmax weights (alpha) per edge ----------------

__global__ __launch_bounds__(256) void alpha1_kernel(const float4* __restrict__ el,
                                                     const float4* __restrict__ er,
                                                     const int* __restrict__ offs,
                                                     const int* __restrict__ ssorted,
                                                     float4* __restrict__ alpha) {
    int n = blockIdx.x * 4 + (threadIdx.x >> 6);
    int l = threadIdx.x & 63;
    int start = offs[n], end = offs[n + 1];
    if (start == end) return;
    float4 ern = er[n];
    float m0 = -INFINITY, m1 = -INFINITY, m2 = -INFINITY, m3 = -INFINITY;
    float s0 = 0.f, s1 = 0.f, s2 = 0.f, s3 = 0.f;
    for (int base = start; base + l < end; base += 64) {
        int sj = ssorted[base + l];
        float4 ev = el[sj];
        float e0 = ev.x + ern.x; e0 = e0 > 0.f ? e0 : NEG_SLOPE * e0;
        float e1 = ev.y + ern.y; e1 = e1 > 0.f ? e1 : NEG_SLOPE * e1;
        float e2 = ev.z + ern.z; e2 = e2 > 0.f ? e2 : NEG_SLOPE * e2;
        float e3 = ev.w + ern.w; e3 = e3 > 0.f ? e3 : NEG_SLOPE * e3;
        float nm;
        nm = fmaxf(m0, e0); s0 = (m0 == nm ? s0 : s0 * __expf(m0 - nm)) + __expf(e0 - nm); m0 = nm;
        nm = fmaxf(m1, e1); s1 = (m1 == nm ? s1 : s1 * __expf(m1 - nm)) + __expf(e1 - nm); m1 = nm;
        nm = fmaxf(m2, e2); s2 = (m2 == nm ? s2 : s2 * __expf(m2 - nm)) + __expf(e2 - nm); m2 = nm;
        nm = fmaxf(m3, e3); s3 = (m3 == nm ? s3 : s3 * __expf(m3 - nm)) + __expf(e3 - nm); m3 = nm;
    }
    #pragma unroll
    for (int o = 1; o < 64; o <<= 1) {
        float om, os, nm, sa, sb;
        om = __shfl_xor(m0, o); os = __shfl_xor(s0, o); nm = fmaxf(m0, om);
        sa = (m0 == nm) ? s0 : s0 * __expf(m0 - nm); sb = (om == nm) ? os : os * __expf(om - nm);
        m0 = nm; s0 = sa + sb;
        om = __shfl_xor(m1, o); os = __shfl_xor(s1, o); nm = fmaxf(m1, om);
        sa = (m1 == nm) ? s1 : s1 * __expf(m1 - nm); sb = (om == nm) ? os : os * __expf(om - nm);
        m1 = nm; s1 = sa + sb;
        om = __shfl_xor(m2, o); os = __shfl_xor(s2, o); nm = fmaxf(m2, om);
        sa = (m2 == nm) ? s2 : s2 * __expf(m2 - nm); sb = (om == nm) ? os : os * __expf(om - nm);
        m2 = nm; s2 = sa + sb;
        om = __shfl_xor(m3, o); os = __shfl_xor(s3, o); nm = fmaxf(m3, om);
        sa = (m3 == nm) ? s3 : s3 * __expf(m3 - nm); sb = (om == nm) ? os : os * __expf(om - nm);
        m3 = nm; s3 = sa + sb;
    }
    float r0 = 1.f / s0, r1 = 1.f / s1, r2 = 1.f / s2, r3 = 1.f / s3;
    for (int base = start; base + l < end; base += 64) {
        int sj = ssorted[base + l];
        float4 ev = el[sj];
        float e0 = ev.x + ern.x; e0 = e0 > 0.f ? e0 : NEG_SLOPE * e0;
        float e1 = ev.y + ern.y; e1 = e1 > 0.f ? e1 : NEG_SLOPE * e1;
        float e2 = ev.z + ern.z; e2 = e2 > 0.f ? e2 : NEG_SLOPE * e2;
        float e3 = ev.w + ern.w; e3 = e3 > 0.f ? e3 : NEG_SLOPE * e3;
        float4 a;
        a.x = __expf(e0 - m0) * r0;
        a.y = __expf(e1 - m1) * r1;
        a.z = __expf(e2 - m2) * r2;
        a.w = __expf(e3 - m3) * r3;
        alpha[base + l] = a;
    }
}

__global__ __launch_bounds__(256) void alpha2_kernel(const float* __restrict__ el,
                                                     const float* __restrict__ er,
                                                     const int* __restrict__ offs,
                                                     const int* __restrict__ ssorted,
                                                     float* __restrict__ alpha) {
    int n = blockIdx.x * 4 + (threadIdx.x >> 6);
    int l = threadIdx.x & 63;
    int start = offs[n], end = offs[n + 1];
    if (start == end) return;
    float ern = er[n];
    float m = -INFINITY, s = 0.f;
    for (int base = start; base + l < end; base += 64) {
        int sj = ssorted[base + l];
        float e = el[sj] + ern; e = e > 0.f ? e : NEG_SLOPE * e;
        float nm = fmaxf(m, e);
        s = (m == nm ? s : s * __expf(m - nm)) + __expf(e - nm);
        m = nm;
    }
    #pragma unroll
    for (int o = 1; o < 64; o <<= 1) {
        float om = __shfl_xor(m, o), os = __shfl_xor(s, o);
        float nm = fmaxf(m, om);
        float sa = (m == nm) ? s : s * __expf(m - nm);
        float sb = (om == nm) ? os : os * __expf(om - nm);
        m = nm; s = sa + sb;
    }
    float r = 1.f / s;
    for (int base = start; base + l < end; base += 64) {
        int sj = ssorted[base + l];
        float e = el[sj] + ern; e = e > 0.f ? e : NEG_SLOPE * e;
        alpha[base + l] = __expf(e - m) * r;
    }
}

// ---------------- weighted aggregation (SpMM), fp16 feature gather ----------
// Layer 1: block = 1 node, 4 waves, x4 unroll -> 16 rows (512B each) in
// flight. Lane l holds cols 4l..4l+3 (half4 = 8B). Emits h1 split-bf16.

__global__ __launch_bounds__(256) void spmm1_kernel(const half4* __restrict__ feat,
                                                    const float* __restrict__ alpha,
                                                    const int* __restrict__ offs,
                                                    const int* __restrict__ ssorted,
                                                    unsigned short* __restrict__ h1hi,
                                                    unsigned short* __restrict__ h1lo) {
    __shared__ float4 red[3][64];
    int n = blockIdx.x;
    int g = threadIdx.x >> 6, l = threadIdx.x & 63;
    int h = l >> 4;
    int start = offs[n], end = offs[n + 1];
    float4 acc = {0.f, 0.f, 0.f, 0.f};
    int pos = start + g;
    for (; pos + 12 < end; pos += 16) {
        int s0 = ssorted[pos], s1 = ssorted[pos + 4],
            s2 = ssorted[pos + 8], s3 = ssorted[pos + 12];
        float a0 = alpha[pos * 4 + h], a1 = alpha[(pos + 4) * 4 + h],
              a2 = alpha[(pos + 8) * 4 + h], a3 = alpha[(pos + 12) * 4 + h];
        half4 f0 = feat[(size_t)s0 * 64 + l];
        half4 f1 = feat[(size_t)s1 * 64 + l];
        half4 f2 = feat[(size_t)s2 * 64 + l];
        half4 f3 = feat[(size_t)s3 * 64 + l];
        acc.x = fmaf(a0, (float)f0[0], acc.x); acc.y = fmaf(a0, (float)f0[1], acc.y);
        acc.z = fmaf(a0, (float)f0[2], acc.z); acc.w = fmaf(a0, (float)f0[3], acc.w);
        acc.x = fmaf(a1, (float)f1[0], acc.x); acc.y = fmaf(a1, (float)f1[1], acc.y);
        acc.z = fmaf(a1, (float)f1[2], acc.z); acc.w = fmaf(a1, (float)f1[3], acc.w);
        acc.x = fmaf(a2, (float)f2[0], acc.x); acc.y = fmaf(a2, (float)f2[1], acc.y);
        acc.z = fmaf(a2, (float)f2[2], acc.z); acc.w = fmaf(a2, (float)f2[3], acc.w);
        acc.x = fmaf(a3, (float)f3[0], acc.x); acc.y = fmaf(a3, (float)f3[1], acc.y);
        acc.z = fmaf(a3, (float)f3[2], acc.z); acc.w = fmaf(a3, (float)f3[3], acc.w);
    }
    for (; pos < end; pos += 4) {
        int s = ssorted[pos];
        float a = alpha[pos * 4 + h];
        half4 f = feat[(size_t)s * 64 + l];
        acc.x = fmaf(a, (float)f[0], acc.x);
        acc.y = fmaf(a, (float)f[1], acc.y);
        acc.z = fmaf(a, (float)f[2], acc.z);
        acc.w = fmaf(a, (float)f[3], acc.w);
    }
    if (g) red[g - 1][l] = acc;
    __syncthreads();
    if (!g) {
        float4 b0 = red[0][l], b1 = red[1][l], b2 = red[2][l];
        acc.x += b0.x + b1.x + b2.x;
        acc.y += b0.y + b1.y + b2.y;
        acc.z += b0.z + b1.z + b2.z;
        acc.w += b0.w + b1.w + b2.w;
        acc.x = acc.x > 0.f ? acc.x : __expf(acc.x) - 1.f;   // ELU
        acc.y = acc.y > 0.f ? acc.y : __expf(acc.y) - 1.f;
        acc.z = acc.z > 0.f ? acc.z : __expf(acc.z) - 1.f;
        acc.w = acc.w > 0.f ? acc.w : __expf(acc.w) - 1.f;
        unsigned short h0 = bf16_rtn(acc.x), h1 = bf16_rtn(acc.y),
                       h2 = bf16_rtn(acc.z), h3 = bf16_rtn(acc.w);
        ushort4 hv = make_ushort4(h0, h1, h2, h3);
        ushort4 lv = make_ushort4(bf16_rtn(acc.x - bf16_to_f32(h0)),
                                  bf16_rtn(acc.y - bf16_to_f32(h1)),
                                  bf16_rtn(acc.z - bf16_to_f32(h2)),
                                  bf16_rtn(acc.w - bf16_to_f32(h3)));
        *(ushort4*)&h1hi[(size_t)n * 256 + l * 4] = hv;
        *(ushort4*)&h1lo[(size_t)n * 256 + l * 4] = lv;
    }
}

// Layer 2: 16 subgroups of 16 lanes, x2 unroll -> 32 rows (128B) in flight.

__global__ __launch_bounds__(256) void spmm2_kernel(const half4* __restrict__ feat,
                                                    const float* __restrict__ alpha,
                                                    const int* __restrict__ offs,
                                                    const int* __restrict__ ssorted,
                                                    float4* __restrict__ out) {
    __shared__ float4 red[3][16];
    int n = blockIdx.x;
    int g = threadIdx.x >> 6, l = threadIdx.x & 63;
    int sub = l >> 4, li = l & 15;
    int start = offs[n], end = offs[n + 1];
    float4 acc = {0.f, 0.f, 0.f, 0.f};
    int pos = start + g * 4 + sub;
    for (; pos + 16 < end; pos += 32) {
        int s0 = ssorted[pos], s1 = ssorted[pos + 16];
        float a0 = alpha[pos], a1 = alpha[pos + 16];
        half4 f0 = feat[(size_t)s0 * 16 + li];
        half4 f1 = feat[(size_t)s1 * 16 + li];
        acc.x = fmaf(a0, (float)f0[0], acc.x); acc.y = fmaf(a0, (float)f0[1], acc.y);
        acc.z = fmaf(a0, (float)f0[2], acc.z); acc.w = fmaf(a0, (float)f0[3], acc.w);
        acc.x = fmaf(a1, (float)f1[0], acc.x); acc.y = fmaf(a1, (float)f1[1], acc.y);
        acc.z = fmaf(a1, (float)f1[2], acc.z); acc.w = fmaf(a1, (float)f1[3], acc.w);
    }
    for (; pos < end; pos += 16) {
        int s = ssorted[pos];
        float a = alpha[pos];
        half4 f = feat[(size_t)s * 16 + li];
        acc.x = fmaf(a, (float)f[0], acc.x);
        acc.y = fmaf(a, (float)f[1], acc.y);
        acc.z = fmaf(a, (float)f[2], acc.z);
        acc.w = fmaf(a, (float)f[3], acc.w);
    }
    #pragma unroll
    for (int o = 16; o < 64; o <<= 1) {
        acc.x += __shfl_xor(acc.x, o);
        acc.y += __shfl_xor(acc.y, o);
        acc.z += __shfl_xor(acc.z, o);
        acc.w += __shfl_xor(acc.w, o);
    }
    if (g && sub == 0) red[g - 1][li] = acc;
    __syncthreads();
    if (!g && sub == 0) {
        float4 b0 = red[0][li], b1 = red[1][li], b2 = red[2][li];
        acc.x += b0.x + b1.x + b2.x;
        acc.y += b0.y + b1.y + b2.y;
        acc.z += b0.z + b1.z + b2.z;
        acc.w += b0.w + b1.w + b2.w;
        out[(size_t)n * 16 + li] = acc;
    }
}

// ---------------- launch ----------------

extern "C" void kernel_launch(void* const* d_in, const int* in_sizes, int n_in,
                              void* d_out, int out_size, void* d_ws, size_t ws_size,
                              hipStream_t stream) {
    const float* x   = (const float*)d_in[0];
    const int*   src = (const int*)d_in[1];
    const int*   dst = (const int*)d_in[2];
    const float* W1  = (const float*)d_in[3];
    const float* al1 = (const float*)d_in[4];
    const float* ar1 = (const float*)d_in[5];
    const float* W2  = (const float*)d_in[6];
    const float* al2 = (const float*)d_in[7];
    const float* ar2 = (const float*)d_in[8];
    float* out = (float*)d_out;

    char* ws = (char*)d_ws;
    size_t off = 0;
    auto alloc = [&](size_t bytes) -> void* {
        void* p = ws + off;
        off += (bytes + 255) & ~(size_t)255;
        return p;
    };
    _Float16* feat1 = (_Float16*)alloc((size_t)NNODES * 256 * 2);             // 25.6 MB
    unsigned short* h1hi = (unsigned short*)alloc((size_t)NNODES * 256 * 2);  // 25.6 MB
    unsigned short* h1lo = (unsigned short*)alloc((size_t)NNODES * 256 * 2);  // 25.6 MB
    unsigned short* W1hi = (unsigned short*)alloc((size_t)256 * 256 * 2);
    unsigned short* W1lo = (unsigned short*)alloc((size_t)256 * 256 * 2);
    unsigned short* W2hi = (unsigned short*)alloc((size_t)64 * 256 * 2);
    unsigned short* W2lo = (unsigned short*)alloc((size_t)64 * 256 * 2);
    float* el1    = (float*)alloc((size_t)NNODES * HEADS * 4);
    float* er1    = (float*)alloc((size_t)NNODES * HEADS * 4);
    float* el2    = (float*)alloc((size_t)NNODES * 4);
    float* er2    = (float*)alloc((size_t)NNODES * 4);
    float* alpha1 = (float*)alloc((size_t)NEDGES * HEADS * 4);                // 12.8 MB
    float* alpha2 = (float*)alloc((size_t)NEDGES * 4);                        // 3.2 MB
    int* deg      = (int*)alloc((size_t)NNODES * 4);
    int* cursor   = (int*)alloc((size_t)NNODES * 4);
    int* offs     = (int*)alloc((size_t)(NNODES + 1) * 4);
    int* bsums    = (int*)alloc((size_t)NB * 4);
    int* ssorted  = (int*)alloc((size_t)NEDGES * 4);
    _Float16* feat2 = feat1;   // feat1 dead after spmm1; reuse for layer 2

    // --- CSR build ---
    hipMemsetAsync(deg, 0, (size_t)NNODES * 4, stream);
    hipMemsetAsync(cursor, 0, (size_t)NNODES * 4, stream);
    hist_kernel<<<(NEDGES + 255) / 256, 256, 0, stream>>>(dst, deg);
    bsum_kernel<<<NB, 256, 0, stream>>>(deg, bsums);
    scan_write_kernel<<<NB, 256, 0, stream>>>(deg, bsums, offs);
    scatter_kernel<<<(NEDGES + 255) / 256, 256, 0, stream>>>(src, dst, offs, cursor, ssorted);

    // --- weight conversions ---
    convert_wt_kernel<<<(256 * 256 + 255) / 256, 256, 0, stream>>>(W1, W1hi, W1lo, 256, 256);
    convert_wt_kernel<<<(256 * 64 + 255) / 256, 256, 0, stream>>>(W2, W2hi, W2lo, 256, 64);

    // --- Layer 1: small-tile LDS-free GEMM (fp32 x split in regs) + el/er ---
    gemm_mfma_kernel<64, false, true><<<dim3(256 / 64, (NNODES + 63) / 64), 256, 0, stream>>>(
        x, nullptr, nullptr, W1hi, W1lo, feat1, al1, ar1, el1, er1, NNODES, 256, 256);
    alpha1_kernel<<<NNODES / 4, 256, 0, stream>>>(
        (const float4*)el1, (const float4*)er1, offs, ssorted, (float4*)alpha1);
    spmm1_kernel<<<NNODES, 256, 0, stream>>>(
        (const half4*)feat1, alpha1, offs, ssorted, h1hi, h1lo);

    // --- Layer 2 ---
    gemm_mfma_kernel<64, true, false><<<dim3(64 / 64, (NNODES + 63) / 64), 256, 0, stream>>>(
        nullptr, h1hi, h1lo, W2hi, W2lo, feat2, nullptr, nullptr, nullptr, nullptr, NNODES, 64, 256);
    elr2_kernel<<<NNODES, 64, 0, stream>>>(feat2, al2, ar2, el2, er2);
    alpha2_kernel<<<NNODES / 4, 256, 0, stream>>>(el2, er2, offs, ssorted, alpha2);
    spmm2_kernel<<<NNODES, 256, 0, stream>>>(
        (const half4*)feat2, alpha2, offs, ssorted, (float4*)out);
}

// Round 9
// 440.480 us; speedup vs baseline: 1.1435x; 1.1435x over previous
//
#include <hip/hip_runtime.h>
#include <math.h>

#define NNODES 50000
#define NEDGES 800000
#define INDIM 256
#define HID 64
#define HEADS 4
#define OUTDIM 64
#define NEG_SLOPE 0.2f
#define NB ((NNODES + 1023) / 1024)   // 49 scan blocks

typedef __attribute__((ext_vector_type(4))) float f32x4;
typedef _Float16 __attribute__((ext_vector_type(4))) half4;
typedef _Float16 __attribute__((ext_vector_type(8))) half8;

// ---------------- CSR build ----------------

__global__ __launch_bounds__(256) void hist_kernel(const int* __restrict__ dst,
                                                   int* __restrict__ deg) {
    int i = blockIdx.x * 256 + threadIdx.x;
    if (i < NEDGES) atomicAdd(&deg[dst[i]], 1);
}

__global__ __launch_bounds__(256) void bsum_kernel(const int* __restrict__ deg,
                                                   int* __restrict__ bsums) {
    int b = blockIdx.x, t = threadIdx.x;
    int base = b * 1024 + t * 4;
    int s = 0;
    #pragma unroll
    for (int e = 0; e < 4; ++e) { int i = base + e; if (i < NNODES) s += deg[i]; }
    #pragma unroll
    for (int o = 32; o; o >>= 1) s += __shfl_xor(s, o);
    __shared__ int ws[4];
    int lane = t & 63, wid = t >> 6;
    if (lane == 0) ws[wid] = s;
    __syncthreads();
    if (t == 0) bsums[b] = ws[0] + ws[1] + ws[2] + ws[3];
}

__global__ __launch_bounds__(256) void scan_write_kernel(const int* __restrict__ deg,
                                                         const int* __restrict__ bsums,
                                                         int* __restrict__ offs) {
    int b = blockIdx.x, t = threadIdx.x;
    int lane = t & 63, wid = t >> 6;
    int bv = (lane < b) ? bsums[lane] : 0;    // b <= NB-1 < 64
    #pragma unroll
    for (int o = 32; o; o >>= 1) bv += __shfl_xor(bv, o);  // block global offset
    int base = b * 1024 + t * 4;
    int v[4]; int tsum = 0;
    #pragma unroll
    for (int e = 0; e < 4; ++e) {
        int i = base + e;
        v[e] = (i < NNODES) ? deg[i] : 0;
        tsum += v[e];
    }
    int p = tsum;
    #pragma unroll
    for (int o = 1; o < 64; o <<= 1) { int u = __shfl_up(p, o); if (lane >= o) p += u; }
    __shared__ int ws[4];
    if (lane == 63) ws[wid] = p;
    __syncthreads();
    int woff = 0;
    for (int i = 0; i < wid; ++i) woff += ws[i];
    int run = bv + woff + p - tsum;           // exclusive prefix for this thread
    #pragma unroll
    for (int e = 0; e < 4; ++e) {
        int i = base + e;
        if (i < NNODES) { offs[i] = run; run += v[e]; }
    }
    if (b == 0 && t == 0) offs[NNODES] = NEDGES;
}

__global__ __launch_bounds__(256) void scatter_kernel(const int* __restrict__ src,
                                                      const int* __restrict__ dst,
                                                      const int* __restrict__ offs,
                                                      int* __restrict__ cursor,
                                                      int* __restrict__ ssorted) {
    int i = blockIdx.x * 256 + threadIdx.x;
    if (i < NEDGES) {
        int d = dst[i];
        int pos = offs[d] + atomicAdd(&cursor[d], 1);
        ssorted[pos] = src[i];
    }
}

// ---------------- weight transpose -> fp16 ----------------
// W [K][N] row-major -> transposed fp16 Wt [N][K]

__global__ __launch_bounds__(256) void convert_wt_kernel(const float* __restrict__ W,
                                                         _Float16* __restrict__ Wt,
                                                         int K, int N) {
    int idx = blockIdx.x * 256 + threadIdx.x;
    if (idx >= K * N) return;
    int k = idx / N, n = idx - k * N;
    Wt[n * K + k] = (_Float16)W[idx];
}

// ---------------- fp16 MFMA GEMM, LDS-free, 128x(BN) tile ----------------
// R8 post-mortem: small tiles doubled FETCH and quartered per-visit MFMA work
// -> worse. R9: revert to R7 geometry (best measured) but replace split-bf16
// (3 MFMA + ~190 VALU split per iter) with plain fp16 MFMA (1 MFMA, 32 cvt).
// A: fp32 (AFP16=false, inline cvt) or fp16 (AFP16=true, e.g. h1). Bt [N][K]
// fp16, L2-resident. K=256 constexpr -> full unroll, compiler hoists loads.
// ELR (BN=128): each wave's 64 cols = one head -> fused el/er epilogue.

template <int BN, bool AFP16, bool ELR>
__global__ __launch_bounds__(256) void gemm_f16_kernel(
        const float* __restrict__ Af, const _Float16* __restrict__ Ah,
        const _Float16* __restrict__ Bt,
        _Float16* __restrict__ C,
        const float* __restrict__ al, const float* __restrict__ ar,
        float* __restrict__ el, float* __restrict__ er,
        int M, int N) {
    constexpr int K = 256;
    constexpr int NT = BN / 32;       // 16-wide n-tiles per wave
    int t = threadIdx.x;
    int lane = t & 63, w = t >> 6;
    int wm = w >> 1, wn = w & 1;
    int lr = lane & 15, quad = lane >> 4;
    int m0 = blockIdx.y * 128, n0 = blockIdx.x * BN;

    f32x4 acc[4][NT];
    #pragma unroll
    for (int i = 0; i < 4; ++i)
        #pragma unroll
        for (int j = 0; j < NT; ++j) acc[i][j] = (f32x4){0.f, 0.f, 0.f, 0.f};

    // A-fragment row per i-tile (clamped; duplicate rows discarded at store)
    int arow[4];
    #pragma unroll
    for (int i = 0; i < 4; ++i) {
        int r = m0 + wm * 64 + i * 16 + lr;
        arow[i] = (r < M) ? r : (M - 1);
    }
    int brow[NT];
    #pragma unroll
    for (int j = 0; j < NT; ++j) brow[j] = n0 + wn * NT * 16 + j * 16 + lr;

    #pragma unroll
    for (int kk = 0; kk < K; kk += 32) {
        half8 a[4], b[NT];
        if (AFP16) {
            #pragma unroll
            for (int i = 0; i < 4; ++i)
                a[i] = *(const half8*)(Ah + (size_t)arow[i] * K + kk + quad * 8);
        } else {
            #pragma unroll
            for (int i = 0; i < 4; ++i) {
                const float* ap = Af + (size_t)arow[i] * K + kk + quad * 8;
                float4 f0 = *(const float4*)ap;
                float4 f1 = *(const float4*)(ap + 4);
                a[i][0] = (_Float16)f0.x; a[i][1] = (_Float16)f0.y;
                a[i][2] = (_Float16)f0.z; a[i][3] = (_Float16)f0.w;
                a[i][4] = (_Float16)f1.x; a[i][5] = (_Float16)f1.y;
                a[i][6] = (_Float16)f1.z; a[i][7] = (_Float16)f1.w;
            }
        }
        #pragma unroll
        for (int j = 0; j < NT; ++j)
            b[j] = *(const half8*)(Bt + (size_t)brow[j] * K + kk + quad * 8);
        #pragma unroll
        for (int i = 0; i < 4; ++i)
            #pragma unroll
            for (int j = 0; j < NT; ++j)
                acc[i][j] = __builtin_amdgcn_mfma_f32_16x16x32_f16(a[i], b[j], acc[i][j], 0, 0, 0);
    }
    #pragma unroll
    for (int i = 0; i < 4; ++i) {
        #pragma unroll
        for (int r = 0; r < 4; ++r) {
            int row = m0 + wm * 64 + i * 16 + quad * 4 + r;
            if (row < M) {
                #pragma unroll
                for (int j = 0; j < NT; ++j)
                    C[(size_t)row * N + n0 + wn * NT * 16 + j * 16 + lr] =
                        (_Float16)acc[i][j][r];
            }
        }
    }
    if (ELR) {
        // wave (wm,wn) covers head h = n0/64 + wn, rows [m0+wm*64, +64)
        int h = n0 / 64 + wn;
        float alh[NT], arh[NT];
        #pragma unroll
        for (int j = 0; j < NT; ++j) {
            alh[j] = al[h * 64 + j * 16 + lr];
            arh[j] = ar[h * 64 + j * 16 + lr];
        }
        #pragma unroll
        for (int i = 0; i < 4; ++i) {
            #pragma unroll
            for (int r = 0; r < 4; ++r) {
                float pel = 0.f, per = 0.f;
                #pragma unroll
                for (int j = 0; j < NT; ++j) {
                    pel = fmaf(acc[i][j][r], alh[j], pel);
                    per = fmaf(acc[i][j][r], arh[j], per);
                }
                #pragma unroll
                for (int o = 1; o < 16; o <<= 1) {
                    pel += __shfl_xor(pel, o);
                    per += __shfl_xor(per, o);
                }
                if (lr == 0) {
                    int row = m0 + wm * 64 + i * 16 + quad * 4 + r;
                    if (row < M) {
                        el[row * HEADS + h] = pel;
                        er[row * HEADS + h] = per;
                    }
                }
            }
        }
    }
}

// ---------------- layer-2 attention dot products ----------------

__global__ __launch_bounds__(64) void elr2_kernel(const _Float16* __restrict__ feat,
                                                  const float* __restrict__ al,
                                                  const float* __restrict__ ar,
                                                  float* __restrict__ el,
                                                  float* __restrict__ er) {
    int n = blockIdx.x, d = threadIdx.x;
    float f = (float)feat[(size_t)n * 64 + d];
    float a = f * al[d], b = f * ar[d];
    #pragma unroll
    for (int o = 32; o; o >>= 1) { a += __shfl_xor(a, o); b += __shfl_xor(b, o); }
    if (d == 0) { el[n] = a; er[n] = b; }
}

// ---------------- softmax weights (alpha) per edge ----------------

__global__ __launch_bounds__(256) void alpha1_kernel(const float4* __restrict__ el,
                                                     const float4* __restrict__ er,
                                                     const int* __restrict__ offs,
                                                     const int* __restrict__ ssorted,
                                                     float4* __restrict__ alpha) {
    int n = blockIdx.x * 4 + (threadIdx.x >> 6);
    int l = threadIdx.x & 63;
    int start = offs[n], end = offs[n + 1];
    if (start == end) return;
    float4 ern = er[n];
    float m0 = -INFINITY, m1 = -INFINITY, m2 = -INFINITY, m3 = -INFINITY;
    float s0 = 0.f, s1 = 0.f, s2 = 0.f, s3 = 0.f;
    for (int base = start; base + l < end; base += 64) {
        int sj = ssorted[base + l];
        float4 ev = el[sj];
        float e0 = ev.x + ern.x; e0 = e0 > 0.f ? e0 : NEG_SLOPE * e0;
        float e1 = ev.y + ern.y; e1 = e1 > 0.f ? e1 : NEG_SLOPE * e1;
        float e2 = ev.z + ern.z; e2 = e2 > 0.f ? e2 : NEG_SLOPE * e2;
        float e3 = ev.w + ern.w; e3 = e3 > 0.f ? e3 : NEG_SLOPE * e3;
        float nm;
        nm = fmaxf(m0, e0); s0 = (m0 == nm ? s0 : s0 * __expf(m0 - nm)) + __expf(e0 - nm); m0 = nm;
        nm = fmaxf(m1, e1); s1 = (m1 == nm ? s1 : s1 * __expf(m1 - nm)) + __expf(e1 - nm); m1 = nm;
        nm = fmaxf(m2, e2); s2 = (m2 == nm ? s2 : s2 * __expf(m2 - nm)) + __expf(e2 - nm); m2 = nm;
        nm = fmaxf(m3, e3); s3 = (m3 == nm ? s3 : s3 * __expf(m3 - nm)) + __expf(e3 - nm); m3 = nm;
    }
    #pragma unroll
    for (int o = 1; o < 64; o <<= 1) {
        float om, os, nm, sa, sb;
        om = __shfl_xor(m0, o); os = __shfl_xor(s0, o); nm = fmaxf(m0, om);
        sa = (m0 == nm) ? s0 : s0 * __expf(m0 - nm); sb = (om == nm) ? os : os * __expf(om - nm);
        m0 = nm; s0 = sa + sb;
        om = __shfl_xor(m1, o); os = __shfl_xor(s1, o); nm = fmaxf(m1, om);
        sa = (m1 == nm) ? s1 : s1 * __expf(m1 - nm); sb = (om == nm) ? os : os * __expf(om - nm);
        m1 = nm; s1 = sa + sb;
        om = __shfl_xor(m2, o); os = __shfl_xor(s2, o); nm = fmaxf(m2, om);
        sa = (m2 == nm) ? s2 : s2 * __expf(m2 - nm); sb = (om == nm) ? os : os * __expf(om - nm);
        m2 = nm; s2 = sa + sb;
        om = __shfl_xor(m3, o); os = __shfl_xor(s3, o); nm = fmaxf(m3, om);
        sa = (m3 == nm) ? s3 : s3 * __expf(m3 - nm); sb = (om == nm) ? os : os * __expf(om - nm);
        m3 = nm; s3 = sa + sb;
    }
    float r0 = 1.f / s0, r1 = 1.f / s1, r2 = 1.f / s2, r3 = 1.f / s3;
    for (int base = start; base + l < end; base += 64) {
        int sj = ssorted[base + l];
        float4 ev = el[sj];
        float e0 = ev.x + ern.x; e0 = e0 > 0.f ? e0 : NEG_SLOPE * e0;
        float e1 = ev.y + ern.y; e1 = e1 > 0.f ? e1 : NEG_SLOPE * e1;
        float e2 = ev.z + ern.z; e2 = e2 > 0.f ? e2 : NEG_SLOPE * e2;
        float e3 = ev.w + ern.w; e3 = e3 > 0.f ? e3 : NEG_SLOPE * e3;
        float4 a;
        a.x = __expf(e0 - m0) * r0;
        a.y = __expf(e1 - m1) * r1;
        a.z = __expf(e2 - m2) * r2;
        a.w = __expf(e3 - m3) * r3;
        alpha[base + l] = a;
    }
}

__global__ __launch_bounds__(256) void alpha2_kernel(const float* __restrict__ el,
                                                     const float* __restrict__ er,
                                                     const int* __restrict__ offs,
                                                     const int* __restrict__ ssorted,
                                                     float* __restrict__ alpha) {
    int n = blockIdx.x * 4 + (threadIdx.x >> 6);
    int l = threadIdx.x & 63;
    int start = offs[n], end = offs[n + 1];
    if (start == end) return;
    float ern = er[n];
    float m = -INFINITY, s = 0.f;
    for (int base = start; base + l < end; base += 64) {
        int sj = ssorted[base + l];
        float e = el[sj] + ern; e = e > 0.f ? e : NEG_SLOPE * e;
        float nm = fmaxf(m, e);
        s = (m == nm ? s : s * __expf(m - nm)) + __expf(e - nm);
        m = nm;
    }
    #pragma unroll
    for (int o = 1; o < 64; o <<= 1) {
        float om = __shfl_xor(m, o), os = __shfl_xor(s, o);
        float nm = fmaxf(m, om);
        float sa = (m == nm) ? s : s * __expf(m - nm);
        float sb = (om == nm) ? os : os * __expf(om - nm);
        m = nm; s = sa + sb;
    }
    float r = 1.f / s;
    for (int base = start; base + l < end; base += 64) {
        int sj = ssorted[base + l];
        float e = el[sj] + ern; e = e > 0.f ? e : NEG_SLOPE * e;
        alpha[base + l] = __expf(e - m) * r;
    }
}

// ---------------- weighted aggregation (SpMM), fp16 feature gather ----------
// Layer 1: block = 1 node, 4 waves, x4 unroll -> 16 rows (512B each) in
// flight. Lane l holds cols 4l..4l+3 (half4 = 8B). Emits h1 fp16.

__global__ __launch_bounds__(256) void spmm1_kernel(const half4* __restrict__ feat,
                                                    const float* __restrict__ alpha,
                                                    const int* __restrict__ offs,
                                                    const int* __restrict__ ssorted,
                                                    _Float16* __restrict__ h1) {
    __shared__ float4 red[3][64];
    int n = blockIdx.x;
    int g = threadIdx.x >> 6, l = threadIdx.x & 63;
    int h = l >> 4;
    int start = offs[n], end = offs[n + 1];
    float4 acc = {0.f, 0.f, 0.f, 0.f};
    int pos = start + g;
    for (; pos + 12 < end; pos += 16) {
        int s0 = ssorted[pos], s1 = ssorted[pos + 4],
            s2 = ssorted[pos + 8], s3 = ssorted[pos + 12];
        float a0 = alpha[pos * 4 + h], a1 = alpha[(pos + 4) * 4 + h],
              a2 = alpha[(pos + 8) * 4 + h], a3 = alpha[(pos + 12) * 4 + h];
        half4 f0 = feat[(size_t)s0 * 64 + l];
        half4 f1 = feat[(size_t)s1 * 64 + l];
        half4 f2 = feat[(size_t)s2 * 64 + l];
        half4 f3 = feat[(size_t)s3 * 64 + l];
        acc.x = fmaf(a0, (float)f0[0], acc.x); acc.y = fmaf(a0, (float)f0[1], acc.y);
        acc.z = fmaf(a0, (float)f0[2], acc.z); acc.w = fmaf(a0, (float)f0[3], acc.w);
        acc.x = fmaf(a1, (float)f1[0], acc.x); acc.y = fmaf(a1, (float)f1[1], acc.y);
        acc.z = fmaf(a1, (float)f1[2], acc.z); acc.w = fmaf(a1, (float)f1[3], acc.w);
        acc.x = fmaf(a2, (float)f2[0], acc.x); acc.y = fmaf(a2, (float)f2[1], acc.y);
        acc.z = fmaf(a2, (float)f2[2], acc.z); acc.w = fmaf(a2, (float)f2[3], acc.w);
        acc.x = fmaf(a3, (float)f3[0], acc.x); acc.y = fmaf(a3, (float)f3[1], acc.y);
        acc.z = fmaf(a3, (float)f3[2], acc.z); acc.w = fmaf(a3, (float)f3[3], acc.w);
    }
    for (; pos < end; pos += 4) {
        int s = ssorted[pos];
        float a = alpha[pos * 4 + h];
        half4 f = feat[(size_t)s * 64 + l];
        acc.x = fmaf(a, (float)f[0], acc.x);
        acc.y = fmaf(a, (float)f[1], acc.y);
        acc.z = fmaf(a, (float)f[2], acc.z);
        acc.w = fmaf(a, (float)f[3], acc.w);
    }
    if (g) red[g - 1][l] = acc;
    __syncthreads();
    if (!g) {
        float4 b0 = red[0][l], b1 = red[1][l], b2 = red[2][l];
        acc.x += b0.x + b1.x + b2.x;
        acc.y += b0.y + b1.y + b2.y;
        acc.z += b0.z + b1.z + b2.z;
        acc.w += b0.w + b1.w + b2.w;
        acc.x = acc.x > 0.f ? acc.x : __expf(acc.x) - 1.f;   // ELU
        acc.y = acc.y > 0.f ? acc.y : __expf(acc.y) - 1.f;
        acc.z = acc.z > 0.f ? acc.z : __expf(acc.z) - 1.f;
        acc.w = acc.w > 0.f ? acc.w : __expf(acc.w) - 1.f;
        half4 hv = {(_Float16)acc.x, (_Float16)acc.y, (_Float16)acc.z, (_Float16)acc.w};
        *(half4*)&h1[(size_t)n * 256 + l * 4] = hv;
    }
}

// Layer 2: 16 subgroups of 16 lanes, x2 unroll -> 32 rows (128B) in flight.

__global__ __launch_bounds__(256) void spmm2_kernel(const half4* __restrict__ feat,
                                                    const float* __restrict__ alpha,
                                                    const int* __restrict__ offs,
                                                    const int* __restrict__ ssorted,
                                                    float4* __restrict__ out) {
    __shared__ float4 red[3][16];
    int n = blockIdx.x;
    int g = threadIdx.x >> 6, l = threadIdx.x & 63;
    int sub = l >> 4, li = l & 15;
    int start = offs[n], end = offs[n + 1];
    float4 acc = {0.f, 0.f, 0.f, 0.f};
    int pos = start + g * 4 + sub;
    for (; pos + 16 < end; pos += 32) {
        int s0 = ssorted[pos], s1 = ssorted[pos + 16];
        float a0 = alpha[pos], a1 = alpha[pos + 16];
        half4 f0 = feat[(size_t)s0 * 16 + li];
        half4 f1 = feat[(size_t)s1 * 16 + li];
        acc.x = fmaf(a0, (float)f0[0], acc.x); acc.y = fmaf(a0, (float)f0[1], acc.y);
        acc.z = fmaf(a0, (float)f0[2], acc.z); acc.w = fmaf(a0, (float)f0[3], acc.w);
        acc.x = fmaf(a1, (float)f1[0], acc.x); acc.y = fmaf(a1, (float)f1[1], acc.y);
        acc.z = fmaf(a1, (float)f1[2], acc.z); acc.w = fmaf(a1, (float)f1[3], acc.w);
    }
    for (; pos < end; pos += 16) {
        int s = ssorted[pos];
        float a = alpha[pos];
        half4 f = feat[(size_t)s * 16 + li];
        acc.x = fmaf(a, (float)f[0], acc.x);
        acc.y = fmaf(a, (float)f[1], acc.y);
        acc.z = fmaf(a, (float)f[2], acc.z);
        acc.w = fmaf(a, (float)f[3], acc.w);
    }
    #pragma unroll
    for (int o = 16; o < 64; o <<= 1) {
        acc.x += __shfl_xor(acc.x, o);
        acc.y += __shfl_xor(acc.y, o);
        acc.z += __shfl_xor(acc.z, o);
        acc.w += __shfl_xor(acc.w, o);
    }
    if (g && sub == 0) red[g - 1][li] = acc;
    __syncthreads();
    if (!g && sub == 0) {
        float4 b0 = red[0][li], b1 = red[1][li], b2 = red[2][li];
        acc.x += b0.x + b1.x + b2.x;
        acc.y += b0.y + b1.y + b2.y;
        acc.z += b0.z + b1.z + b2.z;
        acc.w += b0.w + b1.w + b2.w;
        out[(size_t)n * 16 + li] = acc;
    }
}

// ---------------- launch ----------------

extern "C" void kernel_launch(void* const* d_in, const int* in_sizes, int n_in,
                              void* d_out, int out_size, void* d_ws, size_t ws_size,
                              hipStream_t stream) {
    const float* x   = (const float*)d_in[0];
    const int*   src = (const int*)d_in[1];
    const int*   dst = (const int*)d_in[2];
    const float* W1  = (const float*)d_in[3];
    const float* al1 = (const float*)d_in[4];
    const float* ar1 = (const float*)d_in[5];
    const float* W2  = (const float*)d_in[6];
    const float* al2 = (const float*)d_in[7];
    const float* ar2 = (const float*)d_in[8];
    float* out = (float*)d_out;

    char* ws = (char*)d_ws;
    size_t off = 0;
    auto alloc = [&](size_t bytes) -> void* {
        void* p = ws + off;
        off += (bytes + 255) & ~(size_t)255;
        return p;
    };
    _Float16* feat1 = (_Float16*)alloc((size_t)NNODES * 256 * 2);   // 25.6 MB
    _Float16* h1    = (_Float16*)alloc((size_t)NNODES * 256 * 2);   // 25.6 MB
    _Float16* W1t   = (_Float16*)alloc((size_t)256 * 256 * 2);
    _Float16* W2t   = (_Float16*)alloc((size_t)64 * 256 * 2);
    float* el1    = (float*)alloc((size_t)NNODES * HEADS * 4);
    float* er1    = (float*)alloc((size_t)NNODES * HEADS * 4);
    float* el2    = (float*)alloc((size_t)NNODES * 4);
    float* er2    = (float*)alloc((size_t)NNODES * 4);
    float* alpha1 = (float*)alloc((size_t)NEDGES * HEADS * 4);      // 12.8 MB
    float* alpha2 = (float*)alloc((size_t)NEDGES * 4);              // 3.2 MB
    int* deg      = (int*)alloc((size_t)NNODES * 4);
    int* cursor   = (int*)alloc((size_t)NNODES * 4);
    int* offs     = (int*)alloc((size_t)(NNODES + 1) * 4);
    int* bsums    = (int*)alloc((size_t)NB * 4);
    int* ssorted  = (int*)alloc((size_t)NEDGES * 4);
    _Float16* feat2 = feat1;   // feat1 dead after spmm1; reuse for layer 2

    // --- CSR build ---
    hipMemsetAsync(deg, 0, (size_t)NNODES * 4, stream);
    hipMemsetAsync(cursor, 0, (size_t)NNODES * 4, stream);
    hist_kernel<<<(NEDGES + 255) / 256, 256, 0, stream>>>(dst, deg);
    bsum_kernel<<<NB, 256, 0, stream>>>(deg, bsums);
    scan_write_kernel<<<NB, 256, 0, stream>>>(deg, bsums, offs);
    scatter_kernel<<<(NEDGES + 255) / 256, 256, 0, stream>>>(src, dst, offs, cursor, ssorted);

    // --- weight conversions ---
    convert_wt_kernel<<<(256 * 256 + 255) / 256, 256, 0, stream>>>(W1, W1t, 256, 256);
    convert_wt_kernel<<<(256 * 64 + 255) / 256, 256, 0, stream>>>(W2, W2t, 256, 64);

    // --- Layer 1: fp16 MFMA GEMM (inline fp32->fp16 x) + fused el/er ---
    gemm_f16_kernel<128, false, true><<<dim3(256 / 128, (NNODES + 127) / 128), 256, 0, stream>>>(
        x, nullptr, W1t, feat1, al1, ar1, el1, er1, NNODES, 256);
    alpha1_kernel<<<NNODES / 4, 256, 0, stream>>>(
        (const float4*)el1, (const float4*)er1, offs, ssorted, (float4*)alpha1);
    spmm1_kernel<<<NNODES, 256, 0, stream>>>(
        (const half4*)feat1, alpha1, offs, ssorted, h1);

    // --- Layer 2 ---
    gemm_f16_kernel<64, true, false><<<dim3(64 / 64, (NNODES + 127) / 128), 256, 0, stream>>>(
        nullptr, h1, W2t, feat2, nullptr, nullptr, nullptr, nullptr, NNODES, 64);
    elr2_kernel<<<NNODES, 64, 0, stream>>>(feat2, al2, ar2, el2, er2);
    alpha2_kernel<<<NNODES / 4, 256, 0, stream>>>(el2, er2, offs, ssorted, alpha2);
    spmm2_kernel<<<NNODES, 256, 0, stream>>>(
        (const half4*)feat2, alpha2, offs, ssorted, (float4*)out);
}